// Round 5
// baseline (679.634 us; speedup 1.0000x reference)
//
#include <hip/hip_runtime.h>
#include <stdint.h>

typedef unsigned long long ull;

#define BATCH 16
#define NA 9
#define HH 128
#define WW 128
#define HW (HH*WW)            // 16384
#define NITEMS (NA*HW)        // 147456 per batch
#define PRE 6000
#define POST 300
#define NMS_T 0.7f
#define NBINS 4096            // top-12 bits of sortable key
#define NSLICE 16             // histogram slices per batch
#define CAP 8192
#define CBLK 144              // compact blocks per batch (1024 items each)

__device__ __forceinline__ uint32_t fkey(float f) {
    uint32_t u = __float_as_uint(f);
    return u ^ ((u & 0x80000000u) ? 0xFFFFFFFFu : 0x80000000u);
}

// K1: per-(batch,slice) LDS histogram of top-12 key bits; non-atomic global write
__global__ __launch_bounds__(1024) void k_hist(const float4* __restrict__ scores4,
                                               uint32_t* __restrict__ hist) {
    int b = blockIdx.x / NSLICE;
    int sl = blockIdx.x % NSLICE;
    int t = threadIdx.x;
    __shared__ uint32_t lh[NBINS];
    for (int i = t; i < NBINS; i += 1024) lh[i] = 0;
    __syncthreads();
    size_t base4 = ((size_t)b * (2 * NA * HW) + (size_t)NA * HW) / 4;
    const int PER = NITEMS / NSLICE / 4;          // 2304 float4 per slice
    size_t s4 = base4 + (size_t)sl * PER;
    for (int v = t; v < PER; v += 1024) {
        float4 f = scores4[s4 + v];
        atomicAdd(&lh[fkey(f.x) >> 20], 1u);
        atomicAdd(&lh[fkey(f.y) >> 20], 1u);
        atomicAdd(&lh[fkey(f.z) >> 20], 1u);
        atomicAdd(&lh[fkey(f.w) >> 20], 1u);
    }
    __syncthreads();
    uint32_t* o = hist + ((size_t)b * NSLICE + sl) * NBINS;
    for (int i = t; i < NBINS; i += 1024) o[i] = lh[i];
}

// K2: merge slices; per-bin descending-order segment starts (suffix prefix-sum);
// init binoff = seg_start; find threshold bucket crossing PRE.
__global__ void k_findbucket(const uint32_t* __restrict__ hist, uint32_t* __restrict__ bucket,
                             uint32_t* __restrict__ segst, uint32_t* __restrict__ binoff) {
    int b = blockIdx.x;
    int t = threadIdx.x;                          // 256 threads, 16 bins each
    __shared__ uint32_t csum[256];
    __shared__ uint32_t csuf[257];
    const uint32_t* hb = hist + (size_t)b * NSLICE * NBINS;
    uint32_t binv[16];
    uint32_t s = 0;
    for (int u = 0; u < 16; ++u) {
        uint32_t v = 0;
        for (int sl = 0; sl < NSLICE; ++sl) v += hb[(size_t)sl * NBINS + t * 16 + u];
        binv[u] = v; s += v;
    }
    csum[t] = s;
    __syncthreads();
    if (t == 0) {
        uint32_t acc = 0;
        csuf[256] = 0;
        for (int c = 255; c >= 0; --c) { acc += csum[c]; csuf[c] = acc; }
    }
    __syncthreads();
    uint32_t cum = csuf[t + 1];                   // items in bins strictly above chunk
    uint32_t* stb = segst  + (size_t)b * NBINS;
    uint32_t* bob = binoff + (size_t)b * NBINS;
    for (int u = 15; u >= 0; --u) {
        int bin = t * 16 + u;
        uint32_t c = binv[u];
        stb[bin] = cum;                           // count of items in bins > bin
        bob[bin] = cum;                           // running scatter cursor
        if (cum < PRE && cum + c >= PRE) bucket[b] = (uint32_t)bin;
        cum += c;
    }
}

// K3: scatter passing items directly into their bucket segment (exact bin-level order)
__global__ __launch_bounds__(256) void k_compact(const float4* __restrict__ scores4,
                                                 const uint32_t* __restrict__ bucket,
                                                 uint32_t* __restrict__ binoff,
                                                 ull* __restrict__ pairs) {
    int b = blockIdx.x / CBLK;
    int blk = blockIdx.x % CBLK;
    int t = threadIdx.x;
    uint32_t bkt = bucket[b];
    size_t base4 = ((size_t)b * (2 * NA * HW) + (size_t)NA * HW) / 4;
    float4 f = scores4[base4 + (size_t)blk * 256 + t];
    int item0 = blk * 1024 + t * 4;
    uint32_t* bo = binoff + (size_t)b * NBINS;
    ull* pb = pairs + (size_t)b * CAP;
#define EMIT(J, K) do { \
        uint32_t k_ = (K); \
        if ((k_ >> 20) >= bkt) { \
            int rem = item0 + (J); \
            int c = rem / HW; \
            int pix = rem - c * HW; \
            uint32_t idx = (uint32_t)(pix * NA + c); \
            uint32_t pos_ = atomicAdd(&bo[k_ >> 20], 1u); \
            if (pos_ < CAP) pb[pos_] = ((ull)k_ << 32) | (uint32_t)(~idx); \
        } \
    } while (0)
    EMIT(0, fkey(f.x));
    EMIT(1, fkey(f.y));
    EMIT(2, fkey(f.z));
    EMIT(3, fkey(f.w));
#undef EMIT
}

// K4: exact descending order via within-bucket ranking (bijection onto [0,total)),
// then fused proposal decode + clip. Replaces the 91-phase bitonic sort.
__global__ __launch_bounds__(1024) void k_rank(const ull* __restrict__ pairs,
                                               const uint32_t* __restrict__ bucket,
                                               const uint32_t* __restrict__ segst,
                                               const uint32_t* __restrict__ binoff,
                                               const float* __restrict__ deltas,
                                               const float* __restrict__ im_info,
                                               const float* __restrict__ anchors,
                                               float4* __restrict__ boxes) {
#pragma clang fp contract(off)
    int b = blockIdx.x;
    int t = threadIdx.x;
    __shared__ ull s[CAP];        // 64 KB: scattered items, grouped by bucket
    __shared__ ull dst[PRE];      // 48 KB: final sorted top-PRE
    const uint32_t* st = segst  + (size_t)b * NBINS;
    const uint32_t* en = binoff + (size_t)b * NBINS;   // post-compact = seg ends
    uint32_t total = en[bucket[b]];                    // items in buckets >= threshold
    if (total > CAP) total = CAP;
    for (int p = t; p < CAP; p += 1024)
        s[p] = (p < (int)total) ? pairs[(size_t)b * CAP + p] : 0ull;
    for (int p = t; p < PRE; p += 1024) dst[p] = 0ull;
    __syncthreads();
    for (int p = t; p < (int)total; p += 1024) {
        ull x = s[p];
        int bin = (int)(x >> 52);                 // top 12 bits of key
        uint32_t lo = st[bin], hi = en[bin];
        if (hi > total) hi = total;
        uint32_t r = 0;
        for (uint32_t q = lo; q < hi; ++q)        // LDS broadcast reads (uniform q)
            r += (s[q] > x);
        uint32_t pos = lo + r;                    // exact descending-sort position
        if (pos < PRE) dst[pos] = x;
    }
    __syncthreads();
    // fused proposal decode + clip
    float limx = im_info[b * 3 + 1] - 1.0f;
    float limy = im_info[b * 3 + 0] - 1.0f;
    for (int e = t; e < PRE; e += 1024) {
        int idx = (int)(~((uint32_t)dst[e]));
        int a = idx % NA;
        int cell = idx / NA;
        int wx = cell & (WW - 1);
        int hy = cell >> 7;
        const float* D = deltas + (size_t)b * (4 * NA * HW) + (size_t)(4 * a) * HW + hy * WW + wx;
        float dx = D[0], dy = D[HW], dw = D[2 * HW], dh = D[3 * HW];
        float ax1 = anchors[4 * a + 0], ay1 = anchors[4 * a + 1];
        float ax2 = anchors[4 * a + 2], ay2 = anchors[4 * a + 3];
        float sx = (float)(wx * 16), sy = (float)(hy * 16);
        float x1 = ax1 + sx, y1 = ay1 + sy, x2 = ax2 + sx, y2 = ay2 + sy;
        float w = x2 - x1 + 1.0f;
        float h = y2 - y1 + 1.0f;
        float cx = x1 + 0.5f * w;
        float cy = y1 + 0.5f * h;
        float pcx = dx * w + cx;
        float pcy = dy * h + cy;
        float pw = (float)exp((double)dw) * w;
        float ph = (float)exp((double)dh) * h;
        float px1 = pcx - 0.5f * pw;
        float py1 = pcy - 0.5f * ph;
        float px2 = pcx + 0.5f * pw;
        float py2 = pcy + 0.5f * ph;
        px1 = fminf(fmaxf(px1, 0.0f), limx);
        py1 = fminf(fmaxf(py1, 0.0f), limy);
        px2 = fminf(fmaxf(px2, 0.0f), limx);
        py2 = fminf(fmaxf(py2, 0.0f), limy);
        boxes[(size_t)b * PRE + e] = make_float4(px1, py1, px2, py2);
    }
}

// K6: matrix-greedy NMS. Per 64-candidate round: waves 0-3 build the 64x64
// suppression matrix (one ballot per row), waves 4-15 test candidates vs the
// kept list (kills via one ballot per wave), wave 0 runs the greedy as pure
// bitmask algebra. 2 barriers/round. Exact greedy.
__global__ __launch_bounds__(1024) void k_nms(const float4* __restrict__ boxes,
                                              float* __restrict__ out) {
#pragma clang fp contract(off)
    const int b = blockIdx.x;
    const int t = threadIdx.x;
    const int lane = t & 63;
    const int wv = t >> 6;                 // 0..15
    __shared__ float4 kbox[POST + 64];     // kept boxes, index order
    __shared__ float  karea[POST + 64];
    __shared__ ull    smask[64];           // candidate-vs-candidate rows
    __shared__ ull    killm[12];           // per-wave kill ballots
    __shared__ int    skept;
    if (t == 0) skept = 0;
    __syncthreads();
    const int NR = (PRE + 63) / 64;        // 94
    for (int r = 0; r < NR; ++r) {
        int kept = skept;                  // uniform (post-barrier)
        if (kept >= POST) break;
        int c0 = r * 64;
        int c = c0 + lane;
        bool valid = (c < PRE);
        float4 cb = valid ? boxes[(size_t)b * PRE + c]
                          : make_float4(0.f, 0.f, 0.f, 0.f);
        float ca = (cb.z - cb.x + 1.0f) * (cb.w - cb.y + 1.0f);
        if (wv < 4) {
            for (int ii = 0; ii < 16; ++ii) {
                int i = wv * 16 + ii;
                int ci = c0 + i;
                float4 ib = (ci < PRE) ? boxes[(size_t)b * PRE + ci]
                                       : make_float4(0.f, 0.f, 0.f, 0.f);
                float ia = (ib.z - ib.x + 1.0f) * (ib.w - ib.y + 1.0f);
                float iwr = fminf(ib.z, cb.z) - fmaxf(ib.x, cb.x) + 1.0f;
                float ihr = fminf(ib.w, cb.w) - fmaxf(ib.y, cb.y) + 1.0f;
                bool sup = false;
                if (iwr > 0.0f && ihr > 0.0f) {        // exact: else iou == 0
                    float inter = iwr * ihr;
                    sup = (inter / ((ia + ca) - inter)) > NMS_T;
                }
                ull m = __ballot(sup);
                if (lane == ii) smask[i] = m;
            }
        } else {
            int sl = wv - 4;               // 0..11: slice of kept list
            bool killed = false;
            for (int k = sl; k < kept; k += 12) {
                float4 kb = kbox[k];       // LDS broadcast
                float iwr = fminf(kb.z, cb.z) - fmaxf(kb.x, cb.x) + 1.0f;
                float ihr = fminf(kb.w, cb.w) - fmaxf(kb.y, cb.y) + 1.0f;
                if (iwr > 0.0f && ihr > 0.0f) {
                    float inter = iwr * ihr;
                    if (inter / ((karea[k] + ca) - inter) > NMS_T) { killed = true; break; }
                }
            }
            ull km = __ballot(killed);     // unconditional -> no stale data
            if (lane == 0) killm[sl] = km;
        }
        __syncthreads();                   // B1: matrix + kills visible
        if (wv == 0) {
            ull kill = 0;
            for (int q = 0; q < 12; ++q) kill |= killm[q];   // uniform LDS reads
            ull rem = __ballot(valid) & ~kill;
            ull mymask = smask[lane];
            ull keptm = 0;
            while (rem) {                  // pure bitmask greedy
                int i = __ffsll((long long)rem) - 1;
                keptm |= 1ull << i;
                ull mi = __shfl(mymask, i);            // broadcast row i
                rem &= ~mi;                            // diag bit clears self
                rem &= ~(1ull << i);
            }
            int rank = (int)__popcll(keptm & ((1ull << lane) - 1ull));
            if ((keptm >> lane) & 1ull) {
                kbox[kept + rank] = cb;
                karea[kept + rank] = ca;
            }
            if (lane == 0) skept = kept + (int)__popcll(keptm);
        }
        __syncthreads();                   // B2: kept list + count visible
    }
    int kf = skept < POST ? skept : POST;
    for (int k = t; k < POST; k += 1024) {
        float4 v = (k < kf) ? kbox[k] : make_float4(0.f, 0.f, 0.f, 0.f);
        float* o = out + ((size_t)b * POST + k) * 5;
        o[0] = (float)b;
        o[1] = v.x; o[2] = v.y; o[3] = v.z; o[4] = v.w;
    }
}

extern "C" void kernel_launch(void* const* d_in, const int* in_sizes, int n_in,
                              void* d_out, int out_size, void* d_ws, size_t ws_size,
                              hipStream_t stream) {
    const float* scores  = (const float*)d_in[0];
    const float* deltas  = (const float*)d_in[1];
    const float* im_info = (const float*)d_in[2];
    const float* anchors = (const float*)d_in[3];
    float* out = (float*)d_out;

    char* ws = (char*)d_ws;
    const size_t HIST_B  = (size_t)BATCH * NSLICE * NBINS * 4;   // 4 MiB
    const size_t BKT_B   = 64;
    const size_t SEG_B   = (size_t)BATCH * NBINS * 4;            // 256 KB
    const size_t OFF_B   = (size_t)BATCH * NBINS * 4;            // 256 KB
    const size_t PAIRS_B = (size_t)BATCH * CAP * 8;              // 1 MiB
    uint32_t* hist   = (uint32_t*)ws;
    uint32_t* bkt    = (uint32_t*)(ws + HIST_B);
    uint32_t* segst  = (uint32_t*)(ws + HIST_B + BKT_B);
    uint32_t* binoff = (uint32_t*)(ws + HIST_B + BKT_B + SEG_B);
    ull* pairs       = (ull*)(ws + HIST_B + BKT_B + SEG_B + OFF_B);
    float4* boxes    = (float4*)(ws + HIST_B + BKT_B + SEG_B + OFF_B + PAIRS_B);

    k_hist<<<BATCH * NSLICE, 1024, 0, stream>>>((const float4*)scores, hist);
    k_findbucket<<<BATCH, 256, 0, stream>>>(hist, bkt, segst, binoff);
    k_compact<<<BATCH * CBLK, 256, 0, stream>>>((const float4*)scores, bkt, binoff, pairs);
    k_rank<<<BATCH, 1024, 0, stream>>>(pairs, bkt, segst, binoff, deltas, im_info, anchors, boxes);
    k_nms<<<BATCH, 1024, 0, stream>>>(boxes, out);
}

// Round 6
// 218.953 us; speedup vs baseline: 3.1040x; 3.1040x over previous
//
#include <hip/hip_runtime.h>
#include <stdint.h>

typedef unsigned long long ull;

#define BATCH 16
#define NA 9
#define HH 128
#define WW 128
#define HW (HH*WW)            // 16384
#define NITEMS (NA*HW)        // 147456 per batch
#define PRE 6000
#define POST 300
#define NMS_T 0.7f
#define NBINS 4096            // top-12 bits of sortable key
#define NSLICE 16             // histogram slices per batch
#define CAP 8192
#define CBLK 144              // compact blocks per batch (1024 items each)

__device__ __forceinline__ uint32_t fkey(float f) {
    uint32_t u = __float_as_uint(f);
    return u ^ ((u & 0x80000000u) ? 0xFFFFFFFFu : 0x80000000u);
}

__device__ __forceinline__ ull shfl_xor_u64(ull x, int m) {
    uint32_t lo = (uint32_t)x, hi = (uint32_t)(x >> 32);
    lo = (uint32_t)__shfl_xor((int)lo, m, 64);
    hi = (uint32_t)__shfl_xor((int)hi, m, 64);
    return ((ull)hi << 32) | lo;
}

// K1: per-(batch,slice) LDS histogram of top-12 key bits; non-atomic global write
__global__ __launch_bounds__(1024) void k_hist(const float4* __restrict__ scores4,
                                               uint32_t* __restrict__ hist) {
    int b = blockIdx.x / NSLICE;
    int sl = blockIdx.x % NSLICE;
    int t = threadIdx.x;
    __shared__ uint32_t lh[NBINS];
    for (int i = t; i < NBINS; i += 1024) lh[i] = 0;
    __syncthreads();
    size_t base4 = ((size_t)b * (2 * NA * HW) + (size_t)NA * HW) / 4;
    const int PER = NITEMS / NSLICE / 4;          // 2304 float4 per slice
    size_t s4 = base4 + (size_t)sl * PER;
    for (int v = t; v < PER; v += 1024) {
        float4 f = scores4[s4 + v];
        atomicAdd(&lh[fkey(f.x) >> 20], 1u);
        atomicAdd(&lh[fkey(f.y) >> 20], 1u);
        atomicAdd(&lh[fkey(f.z) >> 20], 1u);
        atomicAdd(&lh[fkey(f.w) >> 20], 1u);
    }
    __syncthreads();
    uint32_t* o = hist + ((size_t)b * NSLICE + sl) * NBINS;
    for (int i = t; i < NBINS; i += 1024) o[i] = lh[i];
}

// K2: merge slices, find bucket where cumulative-from-top crosses PRE; zero cnt
__global__ void k_findbucket(const uint32_t* __restrict__ hist, uint32_t* __restrict__ bucket,
                             uint32_t* __restrict__ cnt) {
    int b = blockIdx.x;
    int t = threadIdx.x;                          // 256 threads, 16 bins each
    if (t == 0) cnt[b] = 0;                       // runs before k_compact (stream order)
    __shared__ uint32_t csum[256];
    __shared__ uint32_t csuf[257];
    const uint32_t* hb = hist + (size_t)b * NSLICE * NBINS;
    uint32_t binv[16];
    uint32_t s = 0;
    for (int u = 0; u < 16; ++u) {
        uint32_t v = 0;
        for (int sl = 0; sl < NSLICE; ++sl) v += hb[(size_t)sl * NBINS + t * 16 + u];
        binv[u] = v; s += v;
    }
    csum[t] = s;
    __syncthreads();
    if (t == 0) {
        uint32_t acc = 0;
        csuf[256] = 0;
        for (int c = 255; c >= 0; --c) { acc += csum[c]; csuf[c] = acc; }
    }
    __syncthreads();
    uint32_t cum = csuf[t + 1];
    for (int u = 15; u >= 0; --u) {
        uint32_t c = binv[u];
        if (cum < PRE && cum + c >= PRE) bucket[b] = (uint32_t)(t * 16 + u);
        cum += c;
    }
}

// K3: compact (key, idx) pairs with bucket >= threshold; ONE global atomic per block
__global__ __launch_bounds__(256) void k_compact(const float4* __restrict__ scores4,
                                                 const uint32_t* __restrict__ bucket,
                                                 uint32_t* __restrict__ cnt,
                                                 ull* __restrict__ pairs) {
    int b = blockIdx.x / CBLK;
    int blk = blockIdx.x % CBLK;
    int t = threadIdx.x;
    int lane = t & 63, wid = t >> 6;
    uint32_t bkt = bucket[b];
    size_t base4 = ((size_t)b * (2 * NA * HW) + (size_t)NA * HW) / 4;
    float4 f = scores4[base4 + (size_t)blk * 256 + t];
    int item0 = blk * 1024 + t * 4;
    uint32_t k0 = fkey(f.x), k1 = fkey(f.y), k2 = fkey(f.z), k3 = fkey(f.w);
    bool p0 = (k0 >> 20) >= bkt, p1 = (k1 >> 20) >= bkt;
    bool p2 = (k2 >> 20) >= bkt, p3 = (k3 >> 20) >= bkt;
    ull m0 = __ballot(p0), m1 = __ballot(p1);
    ull m2 = __ballot(p2), m3 = __ballot(p3);
    uint32_t c0 = (uint32_t)__popcll(m0), c1 = (uint32_t)__popcll(m1);
    uint32_t c2 = (uint32_t)__popcll(m2), c3 = (uint32_t)__popcll(m3);
    uint32_t wcnt = c0 + c1 + c2 + c3;
    __shared__ uint32_t swc[4];
    __shared__ uint32_t sbase;
    if (lane == 0) swc[wid] = wcnt;
    __syncthreads();
    if (t == 0) {
        uint32_t a0 = swc[0], a1 = swc[1], a2 = swc[2], a3 = swc[3];
        uint32_t tot = a0 + a1 + a2 + a3;
        sbase = tot ? atomicAdd(&cnt[b], tot) : 0u;
        swc[0] = 0; swc[1] = a0; swc[2] = a0 + a1; swc[3] = a0 + a1 + a2;
    }
    __syncthreads();
    uint32_t wbase = sbase + swc[wid];
    ull below = ((ull)1 << lane) - 1ull;
    ull* pb = pairs + (size_t)b * CAP;
#define EMIT(J, K, POS) do { \
        int rem = item0 + (J); \
        int c = rem / HW; \
        int pix = rem - c * HW; \
        uint32_t idx = (uint32_t)(pix * NA + c); \
        uint32_t pos_ = (POS); \
        if (pos_ < CAP) pb[pos_] = ((ull)(K) << 32) | (uint32_t)(~idx); \
    } while (0)
    if (p0) EMIT(0, k0, wbase + (uint32_t)__popcll(m0 & below));
    if (p1) EMIT(1, k1, wbase + c0 + (uint32_t)__popcll(m1 & below));
    if (p2) EMIT(2, k2, wbase + c0 + c1 + (uint32_t)__popcll(m2 & below));
    if (p3) EMIT(3, k3, wbase + c0 + c1 + c2 + (uint32_t)__popcll(m3 & below));
#undef EMIT
}

// K4: hybrid register bitonic sort (descending), 8 elems/thread in VGPRs.
// j<=4: register CE; j in 8..256: wave shuffle CE; j>=512: LDS (double-buffered,
// ONE barrier per phase, 10 phases total). Bit-identical to the array bitonic.
// Fused proposal decode + clip epilogue from registers.
__global__ __launch_bounds__(1024) void k_sort(const ull* __restrict__ pairs,
                                               const uint32_t* __restrict__ cnt,
                                               const float* __restrict__ deltas,
                                               const float* __restrict__ im_info,
                                               const float* __restrict__ anchors,
                                               float4* __restrict__ boxes) {
#pragma clang fp contract(off)
    int b = blockIdx.x;
    int t = threadIdx.x;
    __shared__ ull lb[2][CAP];                     // 128 KiB double buffer
    uint32_t n = cnt[b];
    if (n > CAP) n = CAP;
    ull v[8];
#pragma unroll
    for (int r = 0; r < 8; ++r) {
        int e = (t << 3) + r;
        v[r] = (e < (int)n) ? pairs[(size_t)b * CAP + e] : 0ull;
    }
    int phase = 0;
    for (int k = 2; k <= CAP; k <<= 1) {
        for (int j = k >> 1; j > 0; j >>= 1) {
            if (j >= 512) {
                ull* buf = lb[phase & 1];
                ++phase;
#pragma unroll
                for (int r = 0; r < 8; ++r) buf[(t << 3) + r] = v[r];
                __syncthreads();
                int tp = t ^ (j >> 3);
#pragma unroll
                for (int r = 0; r < 8; ++r) {
                    ull pv = buf[(tp << 3) + r];
                    int e = (t << 3) + r;
                    bool up = ((e & k) == 0);
                    bool takeMax = (up == ((e & j) == 0));
                    v[r] = takeMax ? (v[r] >= pv ? v[r] : pv)
                                   : (v[r] <= pv ? v[r] : pv);
                }
            } else if (j >= 8) {
                int lm = j >> 3;
#pragma unroll
                for (int r = 0; r < 8; ++r) {
                    ull pv = shfl_xor_u64(v[r], lm);
                    int e = (t << 3) + r;
                    bool up = ((e & k) == 0);
                    bool takeMax = (up == ((e & j) == 0));
                    v[r] = takeMax ? (v[r] >= pv ? v[r] : pv)
                                   : (v[r] <= pv ? v[r] : pv);
                }
            } else {
#pragma unroll
                for (int r = 0; r < 8; ++r) {
                    if (!(r & j)) {
                        int e = (t << 3) + r;
                        bool up = ((e & k) == 0);
                        ull a = v[r], c = v[r | j];
                        if ((a < c) == up) { v[r] = c; v[r | j] = a; }
                    }
                }
            }
        }
    }
    // fused proposal decode + clip; thread t owns sorted positions t*8..t*8+7
    float limx = im_info[b * 3 + 1] - 1.0f;
    float limy = im_info[b * 3 + 0] - 1.0f;
#pragma unroll
    for (int r = 0; r < 8; ++r) {
        int e = (t << 3) + r;
        if (e >= PRE) break;
        int idx = (int)(~((uint32_t)v[r]));
        int a = idx % NA;
        int cell = idx / NA;
        int wx = cell & (WW - 1);
        int hy = cell >> 7;
        const float* D = deltas + (size_t)b * (4 * NA * HW) + (size_t)(4 * a) * HW + hy * WW + wx;
        float dx = D[0], dy = D[HW], dw = D[2 * HW], dh = D[3 * HW];
        float ax1 = anchors[4 * a + 0], ay1 = anchors[4 * a + 1];
        float ax2 = anchors[4 * a + 2], ay2 = anchors[4 * a + 3];
        float sx = (float)(wx * 16), sy = (float)(hy * 16);
        float x1 = ax1 + sx, y1 = ay1 + sy, x2 = ax2 + sx, y2 = ay2 + sy;
        float w = x2 - x1 + 1.0f;
        float h = y2 - y1 + 1.0f;
        float cx = x1 + 0.5f * w;
        float cy = y1 + 0.5f * h;
        float pcx = dx * w + cx;
        float pcy = dy * h + cy;
        float pw = (float)exp((double)dw) * w;
        float ph = (float)exp((double)dh) * h;
        float px1 = pcx - 0.5f * pw;
        float py1 = pcy - 0.5f * ph;
        float px2 = pcx + 0.5f * pw;
        float py2 = pcy + 0.5f * ph;
        px1 = fminf(fmaxf(px1, 0.0f), limx);
        py1 = fminf(fmaxf(py1, 0.0f), limy);
        px2 = fminf(fmaxf(px2, 0.0f), limx);
        py2 = fminf(fmaxf(py2, 0.0f), limy);
        boxes[(size_t)b * PRE + e] = make_float4(px1, py1, px2, py2);
    }
}

// K6: matrix-greedy NMS. Per 64-candidate round: waves 0-3 build the 64x64
// suppression matrix (one ballot per row), waves 4-15 test candidates vs the
// kept list (kills via one ballot per wave), wave 0 runs the greedy as pure
// bitmask algebra. 2 barriers/round. Exact greedy.
__global__ __launch_bounds__(1024) void k_nms(const float4* __restrict__ boxes,
                                              float* __restrict__ out) {
#pragma clang fp contract(off)
    const int b = blockIdx.x;
    const int t = threadIdx.x;
    const int lane = t & 63;
    const int wv = t >> 6;                 // 0..15
    __shared__ float4 kbox[POST + 64];     // kept boxes, index order
    __shared__ float  karea[POST + 64];
    __shared__ ull    smask[64];           // candidate-vs-candidate rows
    __shared__ ull    killm[12];           // per-wave kill ballots
    __shared__ int    skept;
    if (t == 0) skept = 0;
    __syncthreads();
    const int NR = (PRE + 63) / 64;        // 94
    for (int r = 0; r < NR; ++r) {
        int kept = skept;                  // uniform (post-barrier)
        if (kept >= POST) break;
        int c0 = r * 64;
        int c = c0 + lane;
        bool valid = (c < PRE);
        float4 cb = valid ? boxes[(size_t)b * PRE + c]
                          : make_float4(0.f, 0.f, 0.f, 0.f);
        float ca = (cb.z - cb.x + 1.0f) * (cb.w - cb.y + 1.0f);
        if (wv < 4) {
            for (int ii = 0; ii < 16; ++ii) {
                int i = wv * 16 + ii;
                int ci = c0 + i;
                float4 ib = (ci < PRE) ? boxes[(size_t)b * PRE + ci]
                                       : make_float4(0.f, 0.f, 0.f, 0.f);
                float ia = (ib.z - ib.x + 1.0f) * (ib.w - ib.y + 1.0f);
                float iwr = fminf(ib.z, cb.z) - fmaxf(ib.x, cb.x) + 1.0f;
                float ihr = fminf(ib.w, cb.w) - fmaxf(ib.y, cb.y) + 1.0f;
                bool sup = false;
                if (iwr > 0.0f && ihr > 0.0f) {        // exact: else iou == 0
                    float inter = iwr * ihr;
                    sup = (inter / ((ia + ca) - inter)) > NMS_T;
                }
                ull m = __ballot(sup);
                if (lane == ii) smask[i] = m;
            }
        } else {
            int sl = wv - 4;               // 0..11: slice of kept list
            bool killed = false;
            for (int k = sl; k < kept; k += 12) {
                float4 kb = kbox[k];       // LDS broadcast
                float iwr = fminf(kb.z, cb.z) - fmaxf(kb.x, cb.x) + 1.0f;
                float ihr = fminf(kb.w, cb.w) - fmaxf(kb.y, cb.y) + 1.0f;
                if (iwr > 0.0f && ihr > 0.0f) {
                    float inter = iwr * ihr;
                    if (inter / ((karea[k] + ca) - inter) > NMS_T) { killed = true; break; }
                }
            }
            ull km = __ballot(killed);     // unconditional -> no stale data
            if (lane == 0) killm[sl] = km;
        }
        __syncthreads();                   // B1: matrix + kills visible
        if (wv == 0) {
            ull kill = 0;
            for (int q = 0; q < 12; ++q) kill |= killm[q];   // uniform LDS reads
            ull rem = __ballot(valid) & ~kill;
            ull mymask = smask[lane];
            ull keptm = 0;
            while (rem) {                  // pure bitmask greedy
                int i = __ffsll((long long)rem) - 1;
                keptm |= 1ull << i;
                ull mi = __shfl(mymask, i);            // broadcast row i
                rem &= ~mi;                            // diag bit clears self
                rem &= ~(1ull << i);
            }
            int rank = (int)__popcll(keptm & ((1ull << lane) - 1ull));
            if ((keptm >> lane) & 1ull) {
                kbox[kept + rank] = cb;
                karea[kept + rank] = ca;
            }
            if (lane == 0) skept = kept + (int)__popcll(keptm);
        }
        __syncthreads();                   // B2: kept list + count visible
    }
    int kf = skept < POST ? skept : POST;
    for (int k = t; k < POST; k += 1024) {
        float4 v = (k < kf) ? kbox[k] : make_float4(0.f, 0.f, 0.f, 0.f);
        float* o = out + ((size_t)b * POST + k) * 5;
        o[0] = (float)b;
        o[1] = v.x; o[2] = v.y; o[3] = v.z; o[4] = v.w;
    }
}

extern "C" void kernel_launch(void* const* d_in, const int* in_sizes, int n_in,
                              void* d_out, int out_size, void* d_ws, size_t ws_size,
                              hipStream_t stream) {
    const float* scores  = (const float*)d_in[0];
    const float* deltas  = (const float*)d_in[1];
    const float* im_info = (const float*)d_in[2];
    const float* anchors = (const float*)d_in[3];
    float* out = (float*)d_out;

    char* ws = (char*)d_ws;
    const size_t HIST_B  = (size_t)BATCH * NSLICE * NBINS * 4;   // 4 MiB
    const size_t CNT_B   = 64;
    const size_t BKT_B   = 64;
    const size_t PAIRS_B = (size_t)BATCH * CAP * 8;              // 1 MiB
    uint32_t* hist = (uint32_t*)ws;
    uint32_t* cnt  = (uint32_t*)(ws + HIST_B);
    uint32_t* bkt  = (uint32_t*)(ws + HIST_B + CNT_B);
    ull* pairs     = (ull*)(ws + HIST_B + CNT_B + BKT_B);
    float4* boxes  = (float4*)(ws + HIST_B + CNT_B + BKT_B + PAIRS_B);

    k_hist<<<BATCH * NSLICE, 1024, 0, stream>>>((const float4*)scores, hist);
    k_findbucket<<<BATCH, 256, 0, stream>>>(hist, bkt, cnt);
    k_compact<<<BATCH * CBLK, 256, 0, stream>>>((const float4*)scores, bkt, cnt, pairs);
    k_sort<<<BATCH, 1024, 0, stream>>>(pairs, cnt, deltas, im_info, anchors, boxes);
    k_nms<<<BATCH, 1024, 0, stream>>>(boxes, out);
}

// Round 7
// 199.158 us; speedup vs baseline: 3.4125x; 1.0994x over previous
//
#include <hip/hip_runtime.h>
#include <stdint.h>

typedef unsigned long long ull;

#define BATCH 16
#define NA 9
#define HH 128
#define WW 128
#define HW (HH*WW)            // 16384
#define NITEMS (NA*HW)        // 147456 per batch
#define PRE 6000
#define POST 300
#define NMS_T 0.7f
#define NBINS 4096            // top-12 bits of sortable key
#define NSLICE 16             // histogram slices per batch
#define CAP 8192
#define CBLK 144              // compact blocks per batch (1024 items each)

__device__ __forceinline__ uint32_t fkey(float f) {
    uint32_t u = __float_as_uint(f);
    return u ^ ((u & 0x80000000u) ? 0xFFFFFFFFu : 0x80000000u);
}

__device__ __forceinline__ ull shfl_xor_u64(ull x, int m) {
    uint32_t lo = (uint32_t)x, hi = (uint32_t)(x >> 32);
    lo = (uint32_t)__shfl_xor((int)lo, m, 64);
    hi = (uint32_t)__shfl_xor((int)hi, m, 64);
    return ((ull)hi << 32) | lo;
}

// K1: per-(batch,slice) LDS histogram of top-12 key bits; non-atomic global write
__global__ __launch_bounds__(1024) void k_hist(const float4* __restrict__ scores4,
                                               uint32_t* __restrict__ hist) {
    int b = blockIdx.x / NSLICE;
    int sl = blockIdx.x % NSLICE;
    int t = threadIdx.x;
    __shared__ uint32_t lh[NBINS];
    for (int i = t; i < NBINS; i += 1024) lh[i] = 0;
    __syncthreads();
    size_t base4 = ((size_t)b * (2 * NA * HW) + (size_t)NA * HW) / 4;
    const int PER = NITEMS / NSLICE / 4;          // 2304 float4 per slice
    size_t s4 = base4 + (size_t)sl * PER;
    for (int v = t; v < PER; v += 1024) {
        float4 f = scores4[s4 + v];
        atomicAdd(&lh[fkey(f.x) >> 20], 1u);
        atomicAdd(&lh[fkey(f.y) >> 20], 1u);
        atomicAdd(&lh[fkey(f.z) >> 20], 1u);
        atomicAdd(&lh[fkey(f.w) >> 20], 1u);
    }
    __syncthreads();
    uint32_t* o = hist + ((size_t)b * NSLICE + sl) * NBINS;
    for (int i = t; i < NBINS; i += 1024) o[i] = lh[i];
}

// K2: merge slices, find bucket where cumulative-from-top crosses PRE; zero cnt
__global__ void k_findbucket(const uint32_t* __restrict__ hist, uint32_t* __restrict__ bucket,
                             uint32_t* __restrict__ cnt) {
    int b = blockIdx.x;
    int t = threadIdx.x;                          // 256 threads, 16 bins each
    if (t == 0) cnt[b] = 0;                       // runs before k_compact (stream order)
    __shared__ uint32_t csum[256];
    __shared__ uint32_t csuf[257];
    const uint32_t* hb = hist + (size_t)b * NSLICE * NBINS;
    uint32_t binv[16];
    uint32_t s = 0;
    for (int u = 0; u < 16; ++u) {
        uint32_t v = 0;
        for (int sl = 0; sl < NSLICE; ++sl) v += hb[(size_t)sl * NBINS + t * 16 + u];
        binv[u] = v; s += v;
    }
    csum[t] = s;
    __syncthreads();
    if (t == 0) {
        uint32_t acc = 0;
        csuf[256] = 0;
        for (int c = 255; c >= 0; --c) { acc += csum[c]; csuf[c] = acc; }
    }
    __syncthreads();
    uint32_t cum = csuf[t + 1];
    for (int u = 15; u >= 0; --u) {
        uint32_t c = binv[u];
        if (cum < PRE && cum + c >= PRE) bucket[b] = (uint32_t)(t * 16 + u);
        cum += c;
    }
}

// decode + clip one proposal; store packed sort key and box at compact position.
__device__ __forceinline__ void decode_store(int rem, uint32_t key, uint32_t pos, int b,
                                             const float* __restrict__ deltas,
                                             const float* __restrict__ anchors,
                                             float limx, float limy,
                                             ull* __restrict__ pb, float4* __restrict__ bC) {
#pragma clang fp contract(off)
    int a = rem / HW;                 // anchor channel
    int pix = rem - a * HW;           // h*W + w
    uint32_t idx = (uint32_t)(pix * NA + a);
    // key desc, then ~idx desc (= idx asc); pos never decides ((key,idx) unique)
    pb[pos] = ((ull)key << 32) | ((ull)((~idx) & 0x3FFFFu) << 13) | pos;
    int wx = pix & (WW - 1);
    int hy = pix >> 7;
    const float* D = deltas + (size_t)b * (4 * NA * HW) + (size_t)(4 * a) * HW + hy * WW + wx;
    float dx = D[0], dy = D[HW], dw = D[2 * HW], dh = D[3 * HW];
    float ax1 = anchors[4 * a + 0], ay1 = anchors[4 * a + 1];
    float ax2 = anchors[4 * a + 2], ay2 = anchors[4 * a + 3];
    float sx = (float)(wx * 16), sy = (float)(hy * 16);
    float x1 = ax1 + sx, y1 = ay1 + sy, x2 = ax2 + sx, y2 = ay2 + sy;
    float w = x2 - x1 + 1.0f;
    float h = y2 - y1 + 1.0f;
    float cx = x1 + 0.5f * w;
    float cy = y1 + 0.5f * h;
    float pcx = dx * w + cx;
    float pcy = dy * h + cy;
    float pw = (float)exp((double)dw) * w;
    float ph = (float)exp((double)dh) * h;
    float px1 = pcx - 0.5f * pw;
    float py1 = pcy - 0.5f * ph;
    float px2 = pcx + 0.5f * pw;
    float py2 = pcy + 0.5f * ph;
    px1 = fminf(fmaxf(px1, 0.0f), limx);
    py1 = fminf(fmaxf(py1, 0.0f), limy);
    px2 = fminf(fmaxf(px2, 0.0f), limx);
    py2 = fminf(fmaxf(py2, 0.0f), limy);
    bC[pos] = make_float4(px1, py1, px2, py2);
}

// K3: compact + DECODE at full parallelism (2304 blocks): passing items get a
// compact position via one block-level atomic; box decode's scattered delta
// gather is latency-hidden by chip-wide occupancy.
__global__ __launch_bounds__(256) void k_compact(const float4* __restrict__ scores4,
                                                 const uint32_t* __restrict__ bucket,
                                                 uint32_t* __restrict__ cnt,
                                                 ull* __restrict__ pairs,
                                                 float4* __restrict__ boxesC,
                                                 const float* __restrict__ deltas,
                                                 const float* __restrict__ im_info,
                                                 const float* __restrict__ anchors) {
    int b = blockIdx.x / CBLK;
    int blk = blockIdx.x % CBLK;
    int t = threadIdx.x;
    int lane = t & 63, wid = t >> 6;
    uint32_t bkt = bucket[b];
    size_t base4 = ((size_t)b * (2 * NA * HW) + (size_t)NA * HW) / 4;
    float4 f = scores4[base4 + (size_t)blk * 256 + t];
    int item0 = blk * 1024 + t * 4;
    uint32_t k0 = fkey(f.x), k1 = fkey(f.y), k2 = fkey(f.z), k3 = fkey(f.w);
    bool p0 = (k0 >> 20) >= bkt, p1 = (k1 >> 20) >= bkt;
    bool p2 = (k2 >> 20) >= bkt, p3 = (k3 >> 20) >= bkt;
    ull m0 = __ballot(p0), m1 = __ballot(p1);
    ull m2 = __ballot(p2), m3 = __ballot(p3);
    uint32_t c0 = (uint32_t)__popcll(m0), c1 = (uint32_t)__popcll(m1);
    uint32_t c2 = (uint32_t)__popcll(m2), c3 = (uint32_t)__popcll(m3);
    uint32_t wcnt = c0 + c1 + c2 + c3;
    __shared__ uint32_t swc[4];
    __shared__ uint32_t sbase;
    if (lane == 0) swc[wid] = wcnt;
    __syncthreads();
    if (t == 0) {
        uint32_t a0 = swc[0], a1 = swc[1], a2 = swc[2], a3 = swc[3];
        uint32_t tot = a0 + a1 + a2 + a3;
        sbase = tot ? atomicAdd(&cnt[b], tot) : 0u;
        swc[0] = 0; swc[1] = a0; swc[2] = a0 + a1; swc[3] = a0 + a1 + a2;
    }
    __syncthreads();
    uint32_t wbase = sbase + swc[wid];
    ull below = ((ull)1 << lane) - 1ull;
    ull* pb = pairs + (size_t)b * CAP;
    float4* bC = boxesC + (size_t)b * CAP;
    float limx = im_info[b * 3 + 1] - 1.0f;
    float limy = im_info[b * 3 + 0] - 1.0f;
    uint32_t pos;
    if (p0) { pos = wbase + (uint32_t)__popcll(m0 & below);
              if (pos < CAP) decode_store(item0 + 0, k0, pos, b, deltas, anchors, limx, limy, pb, bC); }
    if (p1) { pos = wbase + c0 + (uint32_t)__popcll(m1 & below);
              if (pos < CAP) decode_store(item0 + 1, k1, pos, b, deltas, anchors, limx, limy, pb, bC); }
    if (p2) { pos = wbase + c0 + c1 + (uint32_t)__popcll(m2 & below);
              if (pos < CAP) decode_store(item0 + 2, k2, pos, b, deltas, anchors, limx, limy, pb, bC); }
    if (p3) { pos = wbase + c0 + c1 + c2 + (uint32_t)__popcll(m3 & below);
              if (pos < CAP) decode_store(item0 + 3, k3, pos, b, deltas, anchors, limx, limy, pb, bC); }
}

// K4: hybrid register bitonic sort (descending), 8 elems/thread in VGPRs.
// j<=4: register CE; j in 8..256: wave shuffle CE; j>=512: LDS double-buffered
// (one barrier per phase, 10 phases). Epilogue permutes pre-decoded boxes via
// the pos field (L2-resident 16B gather — no HBM scatter here).
__global__ __launch_bounds__(1024) void k_sort(const ull* __restrict__ pairs,
                                               const uint32_t* __restrict__ cnt,
                                               const float4* __restrict__ boxesC,
                                               float4* __restrict__ boxes) {
    int b = blockIdx.x;
    int t = threadIdx.x;
    __shared__ ull lb[2][CAP];                     // 128 KiB double buffer
    uint32_t n = cnt[b];
    if (n > CAP) n = CAP;
    ull v[8];
#pragma unroll
    for (int r = 0; r < 8; ++r) {
        int e = (t << 3) + r;
        v[r] = (e < (int)n) ? pairs[(size_t)b * CAP + e] : 0ull;
    }
    int phase = 0;
    for (int k = 2; k <= CAP; k <<= 1) {
        for (int j = k >> 1; j > 0; j >>= 1) {
            if (j >= 512) {
                ull* buf = lb[phase & 1];
                ++phase;
#pragma unroll
                for (int r = 0; r < 8; ++r) buf[(t << 3) + r] = v[r];
                __syncthreads();
                int tp = t ^ (j >> 3);
#pragma unroll
                for (int r = 0; r < 8; ++r) {
                    ull pv = buf[(tp << 3) + r];
                    int e = (t << 3) + r;
                    bool up = ((e & k) == 0);
                    bool takeMax = (up == ((e & j) == 0));
                    v[r] = takeMax ? (v[r] >= pv ? v[r] : pv)
                                   : (v[r] <= pv ? v[r] : pv);
                }
            } else if (j >= 8) {
                int lm = j >> 3;
#pragma unroll
                for (int r = 0; r < 8; ++r) {
                    ull pv = shfl_xor_u64(v[r], lm);
                    int e = (t << 3) + r;
                    bool up = ((e & k) == 0);
                    bool takeMax = (up == ((e & j) == 0));
                    v[r] = takeMax ? (v[r] >= pv ? v[r] : pv)
                                   : (v[r] <= pv ? v[r] : pv);
                }
            } else {
#pragma unroll
                for (int r = 0; r < 8; ++r) {
                    if (!(r & j)) {
                        int e = (t << 3) + r;
                        bool up = ((e & k) == 0);
                        ull a = v[r], c = v[r | j];
                        if ((a < c) == up) { v[r] = c; v[r | j] = a; }
                    }
                }
            }
        }
    }
    const float4* bC = boxesC + (size_t)b * CAP;
#pragma unroll
    for (int r = 0; r < 8; ++r) {
        int e = (t << 3) + r;
        if (e < PRE)
            boxes[(size_t)b * PRE + e] = bC[(uint32_t)(v[r] & 0x1FFFu)];
    }
}

// K6: matrix-greedy NMS. Per 64-candidate round: waves 0-3 build the 64x64
// suppression matrix (one ballot per row), waves 4-15 test candidates vs the
// kept list (kills via one ballot per wave), wave 0 runs the greedy as pure
// bitmask algebra. 2 barriers/round. Exact greedy.
__global__ __launch_bounds__(1024) void k_nms(const float4* __restrict__ boxes,
                                              float* __restrict__ out) {
#pragma clang fp contract(off)
    const int b = blockIdx.x;
    const int t = threadIdx.x;
    const int lane = t & 63;
    const int wv = t >> 6;                 // 0..15
    __shared__ float4 kbox[POST + 64];     // kept boxes, index order
    __shared__ float  karea[POST + 64];
    __shared__ ull    smask[64];           // candidate-vs-candidate rows
    __shared__ ull    killm[12];           // per-wave kill ballots
    __shared__ int    skept;
    if (t == 0) skept = 0;
    __syncthreads();
    const int NR = (PRE + 63) / 64;        // 94
    for (int r = 0; r < NR; ++r) {
        int kept = skept;                  // uniform (post-barrier)
        if (kept >= POST) break;
        int c0 = r * 64;
        int c = c0 + lane;
        bool valid = (c < PRE);
        float4 cb = valid ? boxes[(size_t)b * PRE + c]
                          : make_float4(0.f, 0.f, 0.f, 0.f);
        float ca = (cb.z - cb.x + 1.0f) * (cb.w - cb.y + 1.0f);
        if (wv < 4) {
            for (int ii = 0; ii < 16; ++ii) {
                int i = wv * 16 + ii;
                int ci = c0 + i;
                float4 ib = (ci < PRE) ? boxes[(size_t)b * PRE + ci]
                                       : make_float4(0.f, 0.f, 0.f, 0.f);
                float ia = (ib.z - ib.x + 1.0f) * (ib.w - ib.y + 1.0f);
                float iwr = fminf(ib.z, cb.z) - fmaxf(ib.x, cb.x) + 1.0f;
                float ihr = fminf(ib.w, cb.w) - fmaxf(ib.y, cb.y) + 1.0f;
                bool sup = false;
                if (iwr > 0.0f && ihr > 0.0f) {        // exact: else iou == 0
                    float inter = iwr * ihr;
                    sup = (inter / ((ia + ca) - inter)) > NMS_T;
                }
                ull m = __ballot(sup);
                if (lane == ii) smask[i] = m;
            }
        } else {
            int sl = wv - 4;               // 0..11: slice of kept list
            bool killed = false;
            for (int k = sl; k < kept; k += 12) {
                float4 kb = kbox[k];       // LDS broadcast
                float iwr = fminf(kb.z, cb.z) - fmaxf(kb.x, cb.x) + 1.0f;
                float ihr = fminf(kb.w, cb.w) - fmaxf(kb.y, cb.y) + 1.0f;
                if (iwr > 0.0f && ihr > 0.0f) {
                    float inter = iwr * ihr;
                    if (inter / ((karea[k] + ca) - inter) > NMS_T) { killed = true; break; }
                }
            }
            ull km = __ballot(killed);     // unconditional -> no stale data
            if (lane == 0) killm[sl] = km;
        }
        __syncthreads();                   // B1: matrix + kills visible
        if (wv == 0) {
            ull kill = 0;
            for (int q = 0; q < 12; ++q) kill |= killm[q];   // uniform LDS reads
            ull rem = __ballot(valid) & ~kill;
            ull mymask = smask[lane];
            ull keptm = 0;
            while (rem) {                  // pure bitmask greedy
                int i = __ffsll((long long)rem) - 1;
                keptm |= 1ull << i;
                ull mi = __shfl(mymask, i);            // broadcast row i
                rem &= ~mi;                            // diag bit clears self
                rem &= ~(1ull << i);
            }
            int rank = (int)__popcll(keptm & ((1ull << lane) - 1ull));
            if ((keptm >> lane) & 1ull) {
                kbox[kept + rank] = cb;
                karea[kept + rank] = ca;
            }
            if (lane == 0) skept = kept + (int)__popcll(keptm);
        }
        __syncthreads();                   // B2: kept list + count visible
    }
    int kf = skept < POST ? skept : POST;
    for (int k = t; k < POST; k += 1024) {
        float4 v = (k < kf) ? kbox[k] : make_float4(0.f, 0.f, 0.f, 0.f);
        float* o = out + ((size_t)b * POST + k) * 5;
        o[0] = (float)b;
        o[1] = v.x; o[2] = v.y; o[3] = v.z; o[4] = v.w;
    }
}

extern "C" void kernel_launch(void* const* d_in, const int* in_sizes, int n_in,
                              void* d_out, int out_size, void* d_ws, size_t ws_size,
                              hipStream_t stream) {
    const float* scores  = (const float*)d_in[0];
    const float* deltas  = (const float*)d_in[1];
    const float* im_info = (const float*)d_in[2];
    const float* anchors = (const float*)d_in[3];
    float* out = (float*)d_out;

    char* ws = (char*)d_ws;
    const size_t HIST_B  = (size_t)BATCH * NSLICE * NBINS * 4;   // 4 MiB
    const size_t CNT_B   = 64;
    const size_t BKT_B   = 64;
    const size_t PAIRS_B = (size_t)BATCH * CAP * 8;              // 1 MiB
    const size_t BOXC_B  = (size_t)BATCH * CAP * 16;             // 2 MiB
    uint32_t* hist  = (uint32_t*)ws;
    uint32_t* cnt   = (uint32_t*)(ws + HIST_B);
    uint32_t* bkt   = (uint32_t*)(ws + HIST_B + CNT_B);
    ull* pairs      = (ull*)(ws + HIST_B + CNT_B + BKT_B);
    float4* boxesC  = (float4*)(ws + HIST_B + CNT_B + BKT_B + PAIRS_B);
    float4* boxes   = (float4*)(ws + HIST_B + CNT_B + BKT_B + PAIRS_B + BOXC_B);

    k_hist<<<BATCH * NSLICE, 1024, 0, stream>>>((const float4*)scores, hist);
    k_findbucket<<<BATCH, 256, 0, stream>>>(hist, bkt, cnt);
    k_compact<<<BATCH * CBLK, 256, 0, stream>>>((const float4*)scores, bkt, cnt, pairs,
                                                boxesC, deltas, im_info, anchors);
    k_sort<<<BATCH, 1024, 0, stream>>>(pairs, cnt, boxesC, boxes);
    k_nms<<<BATCH, 1024, 0, stream>>>(boxes, out);
}

// Round 8
// 160.941 us; speedup vs baseline: 4.2229x; 1.2375x over previous
//
#include <hip/hip_runtime.h>
#include <stdint.h>

typedef unsigned long long ull;

#define BATCH 16
#define NA 9
#define HH 128
#define WW 128
#define HW (HH*WW)            // 16384
#define NITEMS (NA*HW)        // 147456 per batch
#define PRE 6000
#define POST 300
#define NMS_T 0.7f
#define NBINS 4096            // top-12 bits of sortable key
#define NSLICE 16             // histogram slices per batch
#define CAP 8192
#define CBLK 144              // compact blocks per batch (1024 items each)
#define S1CH 2048             // per-block chunk for sort stage 1

__device__ __forceinline__ uint32_t fkey(float f) {
    uint32_t u = __float_as_uint(f);
    return u ^ ((u & 0x80000000u) ? 0xFFFFFFFFu : 0x80000000u);
}

__device__ __forceinline__ ull shfl_xor_u64(ull x, int m) {
    uint32_t lo = (uint32_t)x, hi = (uint32_t)(x >> 32);
    lo = (uint32_t)__shfl_xor((int)lo, m, 64);
    hi = (uint32_t)__shfl_xor((int)hi, m, 64);
    return ((ull)hi << 32) | lo;
}

__device__ __forceinline__ ull ce_sel(ull a, ull b, bool takeMax) {
    return takeMax ? (a >= b ? a : b) : (a <= b ? a : b);
}

// K1: per-(batch,slice) LDS histogram of top-12 key bits; non-atomic global write
__global__ __launch_bounds__(1024) void k_hist(const float4* __restrict__ scores4,
                                               uint32_t* __restrict__ hist) {
    int b = blockIdx.x / NSLICE;
    int sl = blockIdx.x % NSLICE;
    int t = threadIdx.x;
    __shared__ uint32_t lh[NBINS];
    for (int i = t; i < NBINS; i += 1024) lh[i] = 0;
    __syncthreads();
    size_t base4 = ((size_t)b * (2 * NA * HW) + (size_t)NA * HW) / 4;
    const int PER = NITEMS / NSLICE / 4;          // 2304 float4 per slice
    size_t s4 = base4 + (size_t)sl * PER;
    for (int v = t; v < PER; v += 1024) {
        float4 f = scores4[s4 + v];
        atomicAdd(&lh[fkey(f.x) >> 20], 1u);
        atomicAdd(&lh[fkey(f.y) >> 20], 1u);
        atomicAdd(&lh[fkey(f.z) >> 20], 1u);
        atomicAdd(&lh[fkey(f.w) >> 20], 1u);
    }
    __syncthreads();
    uint32_t* o = hist + ((size_t)b * NSLICE + sl) * NBINS;
    for (int i = t; i < NBINS; i += 1024) o[i] = lh[i];
}

// K2: merge slices, find bucket where cumulative-from-top crosses PRE; zero cnt
__global__ void k_findbucket(const uint32_t* __restrict__ hist, uint32_t* __restrict__ bucket,
                             uint32_t* __restrict__ cnt) {
    int b = blockIdx.x;
    int t = threadIdx.x;                          // 256 threads, 16 bins each
    if (t == 0) cnt[b] = 0;                       // runs before k_compact (stream order)
    __shared__ uint32_t csum[256];
    __shared__ uint32_t csuf[257];
    const uint32_t* hb = hist + (size_t)b * NSLICE * NBINS;
    uint32_t binv[16];
    uint32_t s = 0;
    for (int u = 0; u < 16; ++u) {
        uint32_t v = 0;
        for (int sl = 0; sl < NSLICE; ++sl) v += hb[(size_t)sl * NBINS + t * 16 + u];
        binv[u] = v; s += v;
    }
    csum[t] = s;
    __syncthreads();
    if (t == 0) {
        uint32_t acc = 0;
        csuf[256] = 0;
        for (int c = 255; c >= 0; --c) { acc += csum[c]; csuf[c] = acc; }
    }
    __syncthreads();
    uint32_t cum = csuf[t + 1];
    for (int u = 15; u >= 0; --u) {
        uint32_t c = binv[u];
        if (cum < PRE && cum + c >= PRE) bucket[b] = (uint32_t)(t * 16 + u);
        cum += c;
    }
}

// decode + clip one proposal; store packed sort key and box at compact position.
__device__ __forceinline__ void decode_store(int rem, uint32_t key, uint32_t pos, int b,
                                             const float* __restrict__ deltas,
                                             const float* __restrict__ anchors,
                                             float limx, float limy,
                                             ull* __restrict__ pb, float4* __restrict__ bC) {
#pragma clang fp contract(off)
    int a = rem / HW;                 // anchor channel
    int pix = rem - a * HW;           // h*W + w
    uint32_t idx = (uint32_t)(pix * NA + a);
    // key desc, then ~idx desc (= idx asc); pos never decides ((key,idx) unique)
    pb[pos] = ((ull)key << 32) | ((ull)((~idx) & 0x3FFFFu) << 13) | pos;
    int wx = pix & (WW - 1);
    int hy = pix >> 7;
    const float* D = deltas + (size_t)b * (4 * NA * HW) + (size_t)(4 * a) * HW + hy * WW + wx;
    float dx = D[0], dy = D[HW], dw = D[2 * HW], dh = D[3 * HW];
    float ax1 = anchors[4 * a + 0], ay1 = anchors[4 * a + 1];
    float ax2 = anchors[4 * a + 2], ay2 = anchors[4 * a + 3];
    float sx = (float)(wx * 16), sy = (float)(hy * 16);
    float x1 = ax1 + sx, y1 = ay1 + sy, x2 = ax2 + sx, y2 = ay2 + sy;
    float w = x2 - x1 + 1.0f;
    float h = y2 - y1 + 1.0f;
    float cx = x1 + 0.5f * w;
    float cy = y1 + 0.5f * h;
    float pcx = dx * w + cx;
    float pcy = dy * h + cy;
    float pw = (float)exp((double)dw) * w;
    float ph = (float)exp((double)dh) * h;
    float px1 = pcx - 0.5f * pw;
    float py1 = pcy - 0.5f * ph;
    float px2 = pcx + 0.5f * pw;
    float py2 = pcy + 0.5f * ph;
    px1 = fminf(fmaxf(px1, 0.0f), limx);
    py1 = fminf(fmaxf(py1, 0.0f), limy);
    px2 = fminf(fmaxf(px2, 0.0f), limx);
    py2 = fminf(fmaxf(py2, 0.0f), limy);
    bC[pos] = make_float4(px1, py1, px2, py2);
}

// K3: compact + DECODE at full parallelism (2304 blocks)
__global__ __launch_bounds__(256) void k_compact(const float4* __restrict__ scores4,
                                                 const uint32_t* __restrict__ bucket,
                                                 uint32_t* __restrict__ cnt,
                                                 ull* __restrict__ pairs,
                                                 float4* __restrict__ boxesC,
                                                 const float* __restrict__ deltas,
                                                 const float* __restrict__ im_info,
                                                 const float* __restrict__ anchors) {
    int b = blockIdx.x / CBLK;
    int blk = blockIdx.x % CBLK;
    int t = threadIdx.x;
    int lane = t & 63, wid = t >> 6;
    uint32_t bkt = bucket[b];
    size_t base4 = ((size_t)b * (2 * NA * HW) + (size_t)NA * HW) / 4;
    float4 f = scores4[base4 + (size_t)blk * 256 + t];
    int item0 = blk * 1024 + t * 4;
    uint32_t k0 = fkey(f.x), k1 = fkey(f.y), k2 = fkey(f.z), k3 = fkey(f.w);
    bool p0 = (k0 >> 20) >= bkt, p1 = (k1 >> 20) >= bkt;
    bool p2 = (k2 >> 20) >= bkt, p3 = (k3 >> 20) >= bkt;
    ull m0 = __ballot(p0), m1 = __ballot(p1);
    ull m2 = __ballot(p2), m3 = __ballot(p3);
    uint32_t c0 = (uint32_t)__popcll(m0), c1 = (uint32_t)__popcll(m1);
    uint32_t c2 = (uint32_t)__popcll(m2), c3 = (uint32_t)__popcll(m3);
    uint32_t wcnt = c0 + c1 + c2 + c3;
    __shared__ uint32_t swc[4];
    __shared__ uint32_t sbase;
    if (lane == 0) swc[wid] = wcnt;
    __syncthreads();
    if (t == 0) {
        uint32_t a0 = swc[0], a1 = swc[1], a2 = swc[2], a3 = swc[3];
        uint32_t tot = a0 + a1 + a2 + a3;
        sbase = tot ? atomicAdd(&cnt[b], tot) : 0u;
        swc[0] = 0; swc[1] = a0; swc[2] = a0 + a1; swc[3] = a0 + a1 + a2;
    }
    __syncthreads();
    uint32_t wbase = sbase + swc[wid];
    ull below = ((ull)1 << lane) - 1ull;
    ull* pb = pairs + (size_t)b * CAP;
    float4* bC = boxesC + (size_t)b * CAP;
    float limx = im_info[b * 3 + 1] - 1.0f;
    float limy = im_info[b * 3 + 0] - 1.0f;
    uint32_t pos;
    if (p0) { pos = wbase + (uint32_t)__popcll(m0 & below);
              if (pos < CAP) decode_store(item0 + 0, k0, pos, b, deltas, anchors, limx, limy, pb, bC); }
    if (p1) { pos = wbase + c0 + (uint32_t)__popcll(m1 & below);
              if (pos < CAP) decode_store(item0 + 1, k1, pos, b, deltas, anchors, limx, limy, pb, bC); }
    if (p2) { pos = wbase + c0 + c1 + (uint32_t)__popcll(m2 & below);
              if (pos < CAP) decode_store(item0 + 2, k2, pos, b, deltas, anchors, limx, limy, pb, bC); }
    if (p3) { pos = wbase + c0 + c1 + c2 + (uint32_t)__popcll(m3 & below);
              if (pos < CAP) decode_store(item0 + 3, k3, pos, b, deltas, anchors, limx, limy, pb, bC); }
}

// K4a: bitonic stages k=2..2048, each 2048-chunk on its own block (64 blocks).
// For k<2048 the global up-bit equals the local one; for k=2048 it is chunk
// parity. 2 elems/thread: j=1 register, j=2..64 shuffle, j=128..1024 LDS
// (double-buffered, stride-9/8 padded -> 4-way instead of 32-way conflicts).
__global__ __launch_bounds__(1024) void k_sort1(ull* __restrict__ pairs,
                                                const uint32_t* __restrict__ cnt) {
    int b = blockIdx.x >> 2;
    int m = blockIdx.x & 3;
    int t = threadIdx.x;
    __shared__ ull lb[2][S1CH + (S1CH >> 3)];
    uint32_t n = cnt[b];
    if (n > CAP) n = CAP;
    ull* pb = pairs + (size_t)b * CAP;
    int base = m * S1CH;
    ull v[2];
#pragma unroll
    for (int r = 0; r < 2; ++r) {
        int e = base + 2 * t + r;
        v[r] = (e < (int)n) ? pb[e] : 0ull;
    }
    int phase = 0;
    for (int k = 2; k <= S1CH; k <<= 1) {
        bool topk = (k == S1CH);
        for (int j = k >> 1; j > 0; j >>= 1) {
            if (j == 1) {
                int el = 2 * t;
                bool up = topk ? ((m & 1) == 0) : ((el & k) == 0);
                ull a = v[0], c = v[1];
                if ((a < c) == up) { v[0] = c; v[1] = a; }
            } else if (j <= 64) {
                int lm = j >> 1;
#pragma unroll
                for (int r = 0; r < 2; ++r) {
                    ull pv = shfl_xor_u64(v[r], lm);
                    int el = 2 * t + r;
                    bool up = topk ? ((m & 1) == 0) : ((el & k) == 0);
                    bool takeMax = (up == ((el & j) == 0));
                    v[r] = ce_sel(v[r], pv, takeMax);
                }
            } else {
                ull* buf = lb[phase & 1];
                ++phase;
#pragma unroll
                for (int r = 0; r < 2; ++r) { int el = 2 * t + r; buf[el + (el >> 3)] = v[r]; }
                __syncthreads();
#pragma unroll
                for (int r = 0; r < 2; ++r) {
                    int el = 2 * t + r;
                    int ep = el ^ j;
                    ull pv = buf[ep + (ep >> 3)];
                    bool up = topk ? ((m & 1) == 0) : ((el & k) == 0);
                    bool takeMax = (up == ((el & j) == 0));
                    v[r] = ce_sel(v[r], pv, takeMax);
                }
            }
        }
    }
#pragma unroll
    for (int r = 0; r < 2; ++r) pb[base + 2 * t + r] = v[r];
}

// K4b: bitonic stages k=4096, 8192 (25 phases) + permute epilogue. 8 elems per
// thread: j<=4 register, j=8..256 shuffle, j>=512 LDS (single 73.7 KB buffer,
// stride-9 padded -> 4-way conflicts, 2 barriers per LDS phase).
__global__ __launch_bounds__(1024) void k_sort2(const ull* __restrict__ pairs,
                                                const float4* __restrict__ boxesC,
                                                float4* __restrict__ boxes) {
    int b = blockIdx.x;
    int t = threadIdx.x;
    __shared__ ull buf[CAP + (CAP >> 3)];          // 9216 u64 = 73728 B
    const ull* pb = pairs + (size_t)b * CAP;
    ull v[8];
#pragma unroll
    for (int r = 0; r < 8; ++r) v[r] = pb[(t << 3) + r];   // fully written by k_sort1
    for (int k = 4096; k <= CAP; k <<= 1) {
        for (int j = k >> 1; j > 0; j >>= 1) {
            if (j >= 512) {
#pragma unroll
                for (int r = 0; r < 8; ++r) { int e = (t << 3) + r; buf[e + (e >> 3)] = v[r]; }
                __syncthreads();
#pragma unroll
                for (int r = 0; r < 8; ++r) {
                    int e = (t << 3) + r;
                    int ep = e ^ j;
                    ull pv = buf[ep + (ep >> 3)];
                    bool up = ((e & k) == 0);
                    bool takeMax = (up == ((e & j) == 0));
                    v[r] = ce_sel(v[r], pv, takeMax);
                }
                __syncthreads();
            } else if (j >= 8) {
                int lm = j >> 3;
#pragma unroll
                for (int r = 0; r < 8; ++r) {
                    ull pv = shfl_xor_u64(v[r], lm);
                    int e = (t << 3) + r;
                    bool up = ((e & k) == 0);
                    bool takeMax = (up == ((e & j) == 0));
                    v[r] = ce_sel(v[r], pv, takeMax);
                }
            } else {
#pragma unroll
                for (int r = 0; r < 8; ++r) {
                    if (!(r & j)) {
                        int e = (t << 3) + r;
                        bool up = ((e & k) == 0);
                        ull a = v[r], c = v[r | j];
                        if ((a < c) == up) { v[r] = c; v[r | j] = a; }
                    }
                }
            }
        }
    }
    const float4* bC = boxesC + (size_t)b * CAP;
#pragma unroll
    for (int r = 0; r < 8; ++r) {
        int e = (t << 3) + r;
        if (e < PRE)
            boxes[(size_t)b * PRE + e] = bC[(uint32_t)(v[r] & 0x1FFFu)];
    }
}

// K6: matrix-greedy NMS (unchanged).
__global__ __launch_bounds__(1024) void k_nms(const float4* __restrict__ boxes,
                                              float* __restrict__ out) {
#pragma clang fp contract(off)
    const int b = blockIdx.x;
    const int t = threadIdx.x;
    const int lane = t & 63;
    const int wv = t >> 6;                 // 0..15
    __shared__ float4 kbox[POST + 64];     // kept boxes, index order
    __shared__ float  karea[POST + 64];
    __shared__ ull    smask[64];           // candidate-vs-candidate rows
    __shared__ ull    killm[12];           // per-wave kill ballots
    __shared__ int    skept;
    if (t == 0) skept = 0;
    __syncthreads();
    const int NR = (PRE + 63) / 64;        // 94
    for (int r = 0; r < NR; ++r) {
        int kept = skept;                  // uniform (post-barrier)
        if (kept >= POST) break;
        int c0 = r * 64;
        int c = c0 + lane;
        bool valid = (c < PRE);
        float4 cb = valid ? boxes[(size_t)b * PRE + c]
                          : make_float4(0.f, 0.f, 0.f, 0.f);
        float ca = (cb.z - cb.x + 1.0f) * (cb.w - cb.y + 1.0f);
        if (wv < 4) {
            for (int ii = 0; ii < 16; ++ii) {
                int i = wv * 16 + ii;
                int ci = c0 + i;
                float4 ib = (ci < PRE) ? boxes[(size_t)b * PRE + ci]
                                       : make_float4(0.f, 0.f, 0.f, 0.f);
                float ia = (ib.z - ib.x + 1.0f) * (ib.w - ib.y + 1.0f);
                float iwr = fminf(ib.z, cb.z) - fmaxf(ib.x, cb.x) + 1.0f;
                float ihr = fminf(ib.w, cb.w) - fmaxf(ib.y, cb.y) + 1.0f;
                bool sup = false;
                if (iwr > 0.0f && ihr > 0.0f) {        // exact: else iou == 0
                    float inter = iwr * ihr;
                    sup = (inter / ((ia + ca) - inter)) > NMS_T;
                }
                ull m = __ballot(sup);
                if (lane == ii) smask[i] = m;
            }
        } else {
            int sl = wv - 4;               // 0..11: slice of kept list
            bool killed = false;
            for (int k = sl; k < kept; k += 12) {
                float4 kb = kbox[k];       // LDS broadcast
                float iwr = fminf(kb.z, cb.z) - fmaxf(kb.x, cb.x) + 1.0f;
                float ihr = fminf(kb.w, cb.w) - fmaxf(kb.y, cb.y) + 1.0f;
                if (iwr > 0.0f && ihr > 0.0f) {
                    float inter = iwr * ihr;
                    if (inter / ((karea[k] + ca) - inter) > NMS_T) { killed = true; break; }
                }
            }
            ull km = __ballot(killed);     // unconditional -> no stale data
            if (lane == 0) killm[sl] = km;
        }
        __syncthreads();                   // B1: matrix + kills visible
        if (wv == 0) {
            ull kill = 0;
            for (int q = 0; q < 12; ++q) kill |= killm[q];   // uniform LDS reads
            ull rem = __ballot(valid) & ~kill;
            ull mymask = smask[lane];
            ull keptm = 0;
            while (rem) {                  // pure bitmask greedy
                int i = __ffsll((long long)rem) - 1;
                keptm |= 1ull << i;
                ull mi = __shfl(mymask, i);            // broadcast row i
                rem &= ~mi;                            // diag bit clears self
                rem &= ~(1ull << i);
            }
            int rank = (int)__popcll(keptm & ((1ull << lane) - 1ull));
            if ((keptm >> lane) & 1ull) {
                kbox[kept + rank] = cb;
                karea[kept + rank] = ca;
            }
            if (lane == 0) skept = kept + (int)__popcll(keptm);
        }
        __syncthreads();                   // B2: kept list + count visible
    }
    int kf = skept < POST ? skept : POST;
    for (int k = t; k < POST; k += 1024) {
        float4 v = (k < kf) ? kbox[k] : make_float4(0.f, 0.f, 0.f, 0.f);
        float* o = out + ((size_t)b * POST + k) * 5;
        o[0] = (float)b;
        o[1] = v.x; o[2] = v.y; o[3] = v.z; o[4] = v.w;
    }
}

extern "C" void kernel_launch(void* const* d_in, const int* in_sizes, int n_in,
                              void* d_out, int out_size, void* d_ws, size_t ws_size,
                              hipStream_t stream) {
    const float* scores  = (const float*)d_in[0];
    const float* deltas  = (const float*)d_in[1];
    const float* im_info = (const float*)d_in[2];
    const float* anchors = (const float*)d_in[3];
    float* out = (float*)d_out;

    char* ws = (char*)d_ws;
    const size_t HIST_B  = (size_t)BATCH * NSLICE * NBINS * 4;   // 4 MiB
    const size_t CNT_B   = 64;
    const size_t BKT_B   = 64;
    const size_t PAIRS_B = (size_t)BATCH * CAP * 8;              // 1 MiB
    const size_t BOXC_B  = (size_t)BATCH * CAP * 16;             // 2 MiB
    uint32_t* hist  = (uint32_t*)ws;
    uint32_t* cnt   = (uint32_t*)(ws + HIST_B);
    uint32_t* bkt   = (uint32_t*)(ws + HIST_B + CNT_B);
    ull* pairs      = (ull*)(ws + HIST_B + CNT_B + BKT_B);
    float4* boxesC  = (float4*)(ws + HIST_B + CNT_B + BKT_B + PAIRS_B);
    float4* boxes   = (float4*)(ws + HIST_B + CNT_B + BKT_B + PAIRS_B + BOXC_B);

    k_hist<<<BATCH * NSLICE, 1024, 0, stream>>>((const float4*)scores, hist);
    k_findbucket<<<BATCH, 256, 0, stream>>>(hist, bkt, cnt);
    k_compact<<<BATCH * CBLK, 256, 0, stream>>>((const float4*)scores, bkt, cnt, pairs,
                                                boxesC, deltas, im_info, anchors);
    k_sort1<<<BATCH * 4, 1024, 0, stream>>>(pairs, cnt);
    k_sort2<<<BATCH, 1024, 0, stream>>>(pairs, boxesC, boxes);
    k_nms<<<BATCH, 1024, 0, stream>>>(boxes, out);
}

// Round 9
// 136.351 us; speedup vs baseline: 4.9845x; 1.1803x over previous
//
#include <hip/hip_runtime.h>
#include <stdint.h>

typedef unsigned long long ull;

#define BATCH 16
#define NA 9
#define HH 128
#define WW 128
#define HW (HH*WW)            // 16384
#define NITEMS (NA*HW)        // 147456 per batch
#define PRE 6000
#define POST 300
#define NMS_T 0.7f
#define NBINS 4096            // top-12 bits of sortable key
#define NSLICE 16             // histogram slices per batch
#define CAP 8192
#define CBLK 144              // compact blocks per batch (1024 items each)
#define S1CH 2048             // per-block chunk for sort stage 1
#define NCH ((PRE + 63) / 64) // 94 NMS candidate chunks
#define CNTSTRIDE 32          // one 128B line per batch counter (atomic contention fix)

__device__ __forceinline__ uint32_t fkey(float f) {
    uint32_t u = __float_as_uint(f);
    return u ^ ((u & 0x80000000u) ? 0xFFFFFFFFu : 0x80000000u);
}

__device__ __forceinline__ ull shfl_xor_u64(ull x, int m) {
    uint32_t lo = (uint32_t)x, hi = (uint32_t)(x >> 32);
    lo = (uint32_t)__shfl_xor((int)lo, m, 64);
    hi = (uint32_t)__shfl_xor((int)hi, m, 64);
    return ((ull)hi << 32) | lo;
}

__device__ __forceinline__ ull ce_sel(ull a, ull b, bool takeMax) {
    return takeMax ? (a >= b ? a : b) : (a <= b ? a : b);
}

// K1: per-(batch,slice) LDS histogram of top-12 key bits; non-atomic global write
__global__ __launch_bounds__(1024) void k_hist(const float4* __restrict__ scores4,
                                               uint32_t* __restrict__ hist) {
    int b = blockIdx.x / NSLICE;
    int sl = blockIdx.x % NSLICE;
    int t = threadIdx.x;
    __shared__ uint32_t lh[NBINS];
    for (int i = t; i < NBINS; i += 1024) lh[i] = 0;
    __syncthreads();
    size_t base4 = ((size_t)b * (2 * NA * HW) + (size_t)NA * HW) / 4;
    const int PER = NITEMS / NSLICE / 4;          // 2304 float4 per slice
    size_t s4 = base4 + (size_t)sl * PER;
    for (int v = t; v < PER; v += 1024) {
        float4 f = scores4[s4 + v];
        atomicAdd(&lh[fkey(f.x) >> 20], 1u);
        atomicAdd(&lh[fkey(f.y) >> 20], 1u);
        atomicAdd(&lh[fkey(f.z) >> 20], 1u);
        atomicAdd(&lh[fkey(f.w) >> 20], 1u);
    }
    __syncthreads();
    uint32_t* o = hist + ((size_t)b * NSLICE + sl) * NBINS;
    for (int i = t; i < NBINS; i += 1024) o[i] = lh[i];
}

// K2: merge slices, find bucket where cumulative-from-top crosses PRE; zero cnt
__global__ void k_findbucket(const uint32_t* __restrict__ hist, uint32_t* __restrict__ bucket,
                             uint32_t* __restrict__ cnt) {
    int b = blockIdx.x;
    int t = threadIdx.x;                          // 256 threads, 16 bins each
    if (t == 0) cnt[b * CNTSTRIDE] = 0;           // runs before k_compact (stream order)
    __shared__ uint32_t csum[256];
    __shared__ uint32_t csuf[257];
    const uint32_t* hb = hist + (size_t)b * NSLICE * NBINS;
    uint32_t binv[16];
    uint32_t s = 0;
    for (int u = 0; u < 16; ++u) {
        uint32_t v = 0;
        for (int sl = 0; sl < NSLICE; ++sl) v += hb[(size_t)sl * NBINS + t * 16 + u];
        binv[u] = v; s += v;
    }
    csum[t] = s;
    __syncthreads();
    if (t == 0) {
        uint32_t acc = 0;
        csuf[256] = 0;
        for (int c = 255; c >= 0; --c) { acc += csum[c]; csuf[c] = acc; }
    }
    __syncthreads();
    uint32_t cum = csuf[t + 1];
    for (int u = 15; u >= 0; --u) {
        uint32_t c = binv[u];
        if (cum < PRE && cum + c >= PRE) bucket[b] = (uint32_t)(t * 16 + u);
        cum += c;
    }
}

// decode + clip one proposal; store packed sort key and box at compact position.
__device__ __forceinline__ void decode_store(int rem, uint32_t key, uint32_t pos, int b,
                                             const float* __restrict__ deltas,
                                             const float* __restrict__ anchors,
                                             float limx, float limy,
                                             ull* __restrict__ pb, float4* __restrict__ bC) {
#pragma clang fp contract(off)
    int a = rem / HW;                 // anchor channel
    int pix = rem - a * HW;           // h*W + w
    uint32_t idx = (uint32_t)(pix * NA + a);
    // key desc, then ~idx desc (= idx asc); pos never decides ((key,idx) unique)
    pb[pos] = ((ull)key << 32) | ((ull)((~idx) & 0x3FFFFu) << 13) | pos;
    int wx = pix & (WW - 1);
    int hy = pix >> 7;
    const float* D = deltas + (size_t)b * (4 * NA * HW) + (size_t)(4 * a) * HW + hy * WW + wx;
    float dx = D[0], dy = D[HW], dw = D[2 * HW], dh = D[3 * HW];
    float ax1 = anchors[4 * a + 0], ay1 = anchors[4 * a + 1];
    float ax2 = anchors[4 * a + 2], ay2 = anchors[4 * a + 3];
    float sx = (float)(wx * 16), sy = (float)(hy * 16);
    float x1 = ax1 + sx, y1 = ay1 + sy, x2 = ax2 + sx, y2 = ay2 + sy;
    float w = x2 - x1 + 1.0f;
    float h = y2 - y1 + 1.0f;
    float cx = x1 + 0.5f * w;
    float cy = y1 + 0.5f * h;
    float pcx = dx * w + cx;
    float pcy = dy * h + cy;
    float pw = (float)exp((double)dw) * w;
    float ph = (float)exp((double)dh) * h;
    float px1 = pcx - 0.5f * pw;
    float py1 = pcy - 0.5f * ph;
    float px2 = pcx + 0.5f * pw;
    float py2 = pcy + 0.5f * ph;
    px1 = fminf(fmaxf(px1, 0.0f), limx);
    py1 = fminf(fmaxf(py1, 0.0f), limy);
    px2 = fminf(fmaxf(px2, 0.0f), limx);
    py2 = fminf(fmaxf(py2, 0.0f), limy);
    bC[pos] = make_float4(px1, py1, px2, py2);
}

// K3: compact + DECODE at full parallelism (2304 blocks); one padded-line atomic per block
__global__ __launch_bounds__(256) void k_compact(const float4* __restrict__ scores4,
                                                 const uint32_t* __restrict__ bucket,
                                                 uint32_t* __restrict__ cnt,
                                                 ull* __restrict__ pairs,
                                                 float4* __restrict__ boxesC,
                                                 const float* __restrict__ deltas,
                                                 const float* __restrict__ im_info,
                                                 const float* __restrict__ anchors) {
    int b = blockIdx.x / CBLK;
    int blk = blockIdx.x % CBLK;
    int t = threadIdx.x;
    int lane = t & 63, wid = t >> 6;
    uint32_t bkt = bucket[b];
    size_t base4 = ((size_t)b * (2 * NA * HW) + (size_t)NA * HW) / 4;
    float4 f = scores4[base4 + (size_t)blk * 256 + t];
    int item0 = blk * 1024 + t * 4;
    uint32_t k0 = fkey(f.x), k1 = fkey(f.y), k2 = fkey(f.z), k3 = fkey(f.w);
    bool p0 = (k0 >> 20) >= bkt, p1 = (k1 >> 20) >= bkt;
    bool p2 = (k2 >> 20) >= bkt, p3 = (k3 >> 20) >= bkt;
    ull m0 = __ballot(p0), m1 = __ballot(p1);
    ull m2 = __ballot(p2), m3 = __ballot(p3);
    uint32_t c0 = (uint32_t)__popcll(m0), c1 = (uint32_t)__popcll(m1);
    uint32_t c2 = (uint32_t)__popcll(m2), c3 = (uint32_t)__popcll(m3);
    uint32_t wcnt = c0 + c1 + c2 + c3;
    __shared__ uint32_t swc[4];
    __shared__ uint32_t sbase;
    if (lane == 0) swc[wid] = wcnt;
    __syncthreads();
    if (t == 0) {
        uint32_t a0 = swc[0], a1 = swc[1], a2 = swc[2], a3 = swc[3];
        uint32_t tot = a0 + a1 + a2 + a3;
        sbase = tot ? atomicAdd(&cnt[b * CNTSTRIDE], tot) : 0u;
        swc[0] = 0; swc[1] = a0; swc[2] = a0 + a1; swc[3] = a0 + a1 + a2;
    }
    __syncthreads();
    uint32_t wbase = sbase + swc[wid];
    ull below = ((ull)1 << lane) - 1ull;
    ull* pb = pairs + (size_t)b * CAP;
    float4* bC = boxesC + (size_t)b * CAP;
    float limx = im_info[b * 3 + 1] - 1.0f;
    float limy = im_info[b * 3 + 0] - 1.0f;
    uint32_t pos;
    if (p0) { pos = wbase + (uint32_t)__popcll(m0 & below);
              if (pos < CAP) decode_store(item0 + 0, k0, pos, b, deltas, anchors, limx, limy, pb, bC); }
    if (p1) { pos = wbase + c0 + (uint32_t)__popcll(m1 & below);
              if (pos < CAP) decode_store(item0 + 1, k1, pos, b, deltas, anchors, limx, limy, pb, bC); }
    if (p2) { pos = wbase + c0 + c1 + (uint32_t)__popcll(m2 & below);
              if (pos < CAP) decode_store(item0 + 2, k2, pos, b, deltas, anchors, limx, limy, pb, bC); }
    if (p3) { pos = wbase + c0 + c1 + c2 + (uint32_t)__popcll(m3 & below);
              if (pos < CAP) decode_store(item0 + 3, k3, pos, b, deltas, anchors, limx, limy, pb, bC); }
}

// K4a: bitonic stages k=2..2048, each 2048-chunk on its own block (64 blocks).
__global__ __launch_bounds__(1024) void k_sort1(ull* __restrict__ pairs,
                                                const uint32_t* __restrict__ cnt) {
    int b = blockIdx.x >> 2;
    int m = blockIdx.x & 3;
    int t = threadIdx.x;
    __shared__ ull lb[2][S1CH + (S1CH >> 3)];
    uint32_t n = cnt[b * CNTSTRIDE];
    if (n > CAP) n = CAP;
    ull* pb = pairs + (size_t)b * CAP;
    int base = m * S1CH;
    ull v[2];
#pragma unroll
    for (int r = 0; r < 2; ++r) {
        int e = base + 2 * t + r;
        v[r] = (e < (int)n) ? pb[e] : 0ull;
    }
    int phase = 0;
    for (int k = 2; k <= S1CH; k <<= 1) {
        bool topk = (k == S1CH);
        for (int j = k >> 1; j > 0; j >>= 1) {
            if (j == 1) {
                int el = 2 * t;
                bool up = topk ? ((m & 1) == 0) : ((el & k) == 0);
                ull a = v[0], c = v[1];
                if ((a < c) == up) { v[0] = c; v[1] = a; }
            } else if (j <= 64) {
                int lm = j >> 1;
#pragma unroll
                for (int r = 0; r < 2; ++r) {
                    ull pv = shfl_xor_u64(v[r], lm);
                    int el = 2 * t + r;
                    bool up = topk ? ((m & 1) == 0) : ((el & k) == 0);
                    bool takeMax = (up == ((el & j) == 0));
                    v[r] = ce_sel(v[r], pv, takeMax);
                }
            } else {
                ull* buf = lb[phase & 1];
                ++phase;
#pragma unroll
                for (int r = 0; r < 2; ++r) { int el = 2 * t + r; buf[el + (el >> 3)] = v[r]; }
                __syncthreads();
#pragma unroll
                for (int r = 0; r < 2; ++r) {
                    int el = 2 * t + r;
                    int ep = el ^ j;
                    ull pv = buf[ep + (ep >> 3)];
                    bool up = topk ? ((m & 1) == 0) : ((el & k) == 0);
                    bool takeMax = (up == ((el & j) == 0));
                    v[r] = ce_sel(v[r], pv, takeMax);
                }
            }
        }
    }
#pragma unroll
    for (int r = 0; r < 2; ++r) pb[base + 2 * t + r] = v[r];
}

// K4b: bitonic stages k=4096, 8192 + permute epilogue.
__global__ __launch_bounds__(1024) void k_sort2(const ull* __restrict__ pairs,
                                                const float4* __restrict__ boxesC,
                                                float4* __restrict__ boxes) {
    int b = blockIdx.x;
    int t = threadIdx.x;
    __shared__ ull buf[CAP + (CAP >> 3)];          // 9216 u64 = 73728 B
    const ull* pb = pairs + (size_t)b * CAP;
    ull v[8];
#pragma unroll
    for (int r = 0; r < 8; ++r) v[r] = pb[(t << 3) + r];   // fully written by k_sort1
    for (int k = 4096; k <= CAP; k <<= 1) {
        for (int j = k >> 1; j > 0; j >>= 1) {
            if (j >= 512) {
#pragma unroll
                for (int r = 0; r < 8; ++r) { int e = (t << 3) + r; buf[e + (e >> 3)] = v[r]; }
                __syncthreads();
#pragma unroll
                for (int r = 0; r < 8; ++r) {
                    int e = (t << 3) + r;
                    int ep = e ^ j;
                    ull pv = buf[ep + (ep >> 3)];
                    bool up = ((e & k) == 0);
                    bool takeMax = (up == ((e & j) == 0));
                    v[r] = ce_sel(v[r], pv, takeMax);
                }
                __syncthreads();
            } else if (j >= 8) {
                int lm = j >> 3;
#pragma unroll
                for (int r = 0; r < 8; ++r) {
                    ull pv = shfl_xor_u64(v[r], lm);
                    int e = (t << 3) + r;
                    bool up = ((e & k) == 0);
                    bool takeMax = (up == ((e & j) == 0));
                    v[r] = ce_sel(v[r], pv, takeMax);
                }
            } else {
#pragma unroll
                for (int r = 0; r < 8; ++r) {
                    if (!(r & j)) {
                        int e = (t << 3) + r;
                        bool up = ((e & k) == 0);
                        ull a = v[r], c = v[r | j];
                        if ((a < c) == up) { v[r] = c; v[r | j] = a; }
                    }
                }
            }
        }
    }
    const float4* bC = boxesC + (size_t)b * CAP;
#pragma unroll
    for (int r = 0; r < 8; ++r) {
        int e = (t << 3) + r;
        if (e < PRE)
            boxes[(size_t)b * PRE + e] = bC[(uint32_t)(v[r] & 0x1FFFu)];
    }
}

// K5: precompute the 64x64 diagonal suppression matrices for ALL chunks in
// parallel (1504 blocks) — removes the matrix build from k_nms's serial rounds.
// Bit-identical IoU code.
__global__ __launch_bounds__(256) void k_diag(const float4* __restrict__ boxes,
                                              ull* __restrict__ smaskG) {
#pragma clang fp contract(off)
    int b = blockIdx.x / NCH;
    int ch = blockIdx.x % NCH;
    int lane = threadIdx.x & 63;
    int wv = threadIdx.x >> 6;             // 0..3
    int c0 = ch * 64;
    int c = c0 + lane;
    float4 cb = (c < PRE) ? boxes[(size_t)b * PRE + c] : make_float4(0.f, 0.f, 0.f, 0.f);
    float ca = (cb.z - cb.x + 1.0f) * (cb.w - cb.y + 1.0f);
    ull* mrow = smaskG + ((size_t)b * NCH + ch) * 64;
    for (int ii = 0; ii < 16; ++ii) {
        int i = wv * 16 + ii;
        int ci = c0 + i;
        float4 ib = (ci < PRE) ? boxes[(size_t)b * PRE + ci] : make_float4(0.f, 0.f, 0.f, 0.f);
        float ia = (ib.z - ib.x + 1.0f) * (ib.w - ib.y + 1.0f);
        float iwr = fminf(ib.z, cb.z) - fmaxf(ib.x, cb.x) + 1.0f;
        float ihr = fminf(ib.w, cb.w) - fmaxf(ib.y, cb.y) + 1.0f;
        bool sup = false;
        if (iwr > 0.0f && ihr > 0.0f) {    // exact: else iou == 0
            float inter = iwr * ihr;
            sup = (inter / ((ia + ca) - inter)) > NMS_T;
        }
        ull m = __ballot(sup);
        if (lane == 0) mrow[i] = m;
    }
}

// K6: matrix-greedy NMS with precomputed masks. Per round: all 16 waves test
// candidates vs kept list (2x-unrolled strided slices), wave 0 preloads its
// mask row, barrier, wave-0 bitmask greedy, barrier. Exact greedy.
__global__ __launch_bounds__(1024) void k_nms(const float4* __restrict__ boxes,
                                              const ull* __restrict__ smaskG,
                                              float* __restrict__ out) {
#pragma clang fp contract(off)
    const int b = blockIdx.x;
    const int t = threadIdx.x;
    const int lane = t & 63;
    const int wv = t >> 6;                 // 0..15
    __shared__ float4 kbox[POST + 64];     // kept boxes, index order
    __shared__ float  karea[POST + 64];
    __shared__ ull    killm[16];
    __shared__ int    skept;
    if (t == 0) skept = 0;
    __syncthreads();
    for (int r = 0; r < NCH; ++r) {
        int kept = skept;                  // uniform (post-barrier)
        if (kept >= POST) break;
        int c0 = r * 64;
        int c = c0 + lane;
        bool valid = (c < PRE);
        float4 cb = valid ? boxes[(size_t)b * PRE + c]
                          : make_float4(0.f, 0.f, 0.f, 0.f);
        float ca = (cb.z - cb.x + 1.0f) * (cb.w - cb.y + 1.0f);
        ull rowmask = 0;
        if (wv == 0) rowmask = smaskG[((size_t)b * NCH + r) * 64 + lane];  // hidden under vs-kept
        // vs-kept: slice wv of 16, unrolled x2 to halve the LDS dependency chain
        bool killed = false;
        for (int k = wv; k < kept; k += 32) {
            float4 kb1 = kbox[k];
            float a1 = karea[k];
            float iw1 = fminf(kb1.z, cb.z) - fmaxf(kb1.x, cb.x) + 1.0f;
            float ih1 = fminf(kb1.w, cb.w) - fmaxf(kb1.y, cb.y) + 1.0f;
            bool kk = false;
            if (iw1 > 0.0f && ih1 > 0.0f) {
                float inter = iw1 * ih1;
                kk = (inter / ((a1 + ca) - inter)) > NMS_T;
            }
            int k2 = k + 16;
            if (k2 < kept) {
                float4 kb2 = kbox[k2];
                float a2 = karea[k2];
                float iw2 = fminf(kb2.z, cb.z) - fmaxf(kb2.x, cb.x) + 1.0f;
                float ih2 = fminf(kb2.w, cb.w) - fmaxf(kb2.y, cb.y) + 1.0f;
                if (iw2 > 0.0f && ih2 > 0.0f) {
                    float inter2 = iw2 * ih2;
                    kk |= (inter2 / ((a2 + ca) - inter2)) > NMS_T;
                }
            }
            if (kk) { killed = true; break; }
        }
        ull km = __ballot(killed);         // unconditional -> no stale data
        if (lane == 0) killm[wv] = km;
        __syncthreads();                   // B1: kills visible
        if (wv == 0) {
            ull kill = 0;
#pragma unroll
            for (int q = 0; q < 16; ++q) kill |= killm[q];   // uniform LDS reads
            ull rem = __ballot(valid) & ~kill;
            ull keptm = 0;
            while (rem) {                  // pure bitmask greedy
                int i = __ffsll((long long)rem) - 1;
                keptm |= 1ull << i;
                ull mi = __shfl(rowmask, i);           // broadcast row i
                rem &= ~mi;                            // diag bit clears self
                rem &= ~(1ull << i);
            }
            int rank = (int)__popcll(keptm & ((1ull << lane) - 1ull));
            if ((keptm >> lane) & 1ull) {
                kbox[kept + rank] = cb;
                karea[kept + rank] = ca;
            }
            if (lane == 0) skept = kept + (int)__popcll(keptm);
        }
        __syncthreads();                   // B2: kept list + count visible
    }
    int kf = skept < POST ? skept : POST;
    for (int k = t; k < POST; k += 1024) {
        float4 v = (k < kf) ? kbox[k] : make_float4(0.f, 0.f, 0.f, 0.f);
        float* o = out + ((size_t)b * POST + k) * 5;
        o[0] = (float)b;
        o[1] = v.x; o[2] = v.y; o[3] = v.z; o[4] = v.w;
    }
}

extern "C" void kernel_launch(void* const* d_in, const int* in_sizes, int n_in,
                              void* d_out, int out_size, void* d_ws, size_t ws_size,
                              hipStream_t stream) {
    const float* scores  = (const float*)d_in[0];
    const float* deltas  = (const float*)d_in[1];
    const float* im_info = (const float*)d_in[2];
    const float* anchors = (const float*)d_in[3];
    float* out = (float*)d_out;

    char* ws = (char*)d_ws;
    const size_t HIST_B  = (size_t)BATCH * NSLICE * NBINS * 4;   // 4 MiB
    const size_t CNT_B   = (size_t)BATCH * CNTSTRIDE * 4;        // 2 KiB (padded lines)
    const size_t BKT_B   = 64;
    const size_t PAIRS_B = (size_t)BATCH * CAP * 8;              // 1 MiB
    const size_t BOXC_B  = (size_t)BATCH * CAP * 16;             // 2 MiB
    const size_t BOX_B   = (size_t)BATCH * PRE * 16;             // 1.5 MiB
    uint32_t* hist  = (uint32_t*)ws;
    uint32_t* cnt   = (uint32_t*)(ws + HIST_B);
    uint32_t* bkt   = (uint32_t*)(ws + HIST_B + CNT_B);
    ull* pairs      = (ull*)(ws + HIST_B + CNT_B + BKT_B);
    float4* boxesC  = (float4*)(ws + HIST_B + CNT_B + BKT_B + PAIRS_B);
    float4* boxes   = (float4*)(ws + HIST_B + CNT_B + BKT_B + PAIRS_B + BOXC_B);
    ull* smaskG     = (ull*)(ws + HIST_B + CNT_B + BKT_B + PAIRS_B + BOXC_B + BOX_B);

    k_hist<<<BATCH * NSLICE, 1024, 0, stream>>>((const float4*)scores, hist);
    k_findbucket<<<BATCH, 256, 0, stream>>>(hist, bkt, cnt);
    k_compact<<<BATCH * CBLK, 256, 0, stream>>>((const float4*)scores, bkt, cnt, pairs,
                                                boxesC, deltas, im_info, anchors);
    k_sort1<<<BATCH * 4, 1024, 0, stream>>>(pairs, cnt);
    k_sort2<<<BATCH, 1024, 0, stream>>>(pairs, boxesC, boxes);
    k_diag<<<BATCH * NCH, 256, 0, stream>>>(boxes, smaskG);
    k_nms<<<BATCH, 1024, 0, stream>>>(boxes, smaskG, out);
}